// Round 2
// baseline (2291.499 us; speedup 1.0000x reference)
//
#include <hip/hip_runtime.h>

// BaseProtonet: inv_d[n,p] = 1/(mse(f_n,proto_p)+1e-5), labels[n] = plabels[argmax_p inv_d]
// msed = ||f||^2 - 2 f.p + ||p||^2  (= 64*mse), argmax inv_d == argmin msed.
//
// Round 4: invert the mapping. thread = ROW, protos staged once in LDS.
//  Round-3 PMC: dur 492us at VALUBusy 43%, HBM 8%, occupancy 30% -> not a pipe
//  roofline; the thread=proto structure pays per-row: 2 barriers + 18 swizzles
//  (fs butterfly + top2 butterfly) + LDS combine + IEEE div ~= the 64 dot FMAs.
//  FMA floor is 55us; we were 9x over it.
//  This version: each thread holds its feature row in 64 pinned VGPRs and scans
//  all 256 protos from LDS (wave-uniform broadcast reads, conflict-free).
//   - main loop: NO barriers, NO shuffles; argmin + top-2 are 4 local ops/proto.
//   - inv_d via v_rcp + 1 Newton step (value-only; argmin uses raw msed).
//   - float4-buffered inv_d stores.
//   - rescue (b2-b1 < MARGIN, un-quantized fp32 -> strictly tighter trigger than
//     the validated quantized-key version): wave-cooperative fp64 redo with the
//     EXACT validated recipe (butterfly fsd, 4-acc serial-k dot, s_p2d serial
//     order, min with smallest-index tie-break). ~1 rescue per wave expected.
//  Block 512, LDS 67KB -> 2 blocks/CU = 4 waves/SIMD; launch_bounds caps 128 VGPR.

#define PROTOS 256
#define DIM 64
#define MARGIN 0.125f
#define BLOCK 512

__global__ __launch_bounds__(BLOCK, 4)
void protonet_kernel(const float* __restrict__ feats,
                     const float* __restrict__ protos,
                     const int* __restrict__ plabels,
                     float* __restrict__ out_inv,
                     float* __restrict__ out_lab,
                     int rows_total)
{
    __shared__ float  s_pr[PROTOS][DIM];   // 64 KB
    __shared__ float  s_p2f[PROTOS];       // 1 KB
    __shared__ double s_p2d[PROTOS];       // 2 KB

    // ---- stage prototypes (coalesced float4) ----
    {
        const float4* src = (const float4*)protos;
        float4* dst = (float4*)&s_pr[0][0];
        #pragma unroll
        for (int t = 0; t < (PROTOS * DIM / 4) / BLOCK; ++t)
            dst[t * BLOCK + threadIdx.x] = src[t * BLOCK + threadIdx.x];
    }
    __syncthreads();

    // ---- ||p||^2 per proto: fp64 serial-k order (exact validated recipe) ----
    if (threadIdx.x < PROTOS) {
        const int p = threadIdx.x;
        const float4* q4 = (const float4*)&s_pr[p][0];
        double acc = 0.0;
        #pragma unroll
        for (int i = 0; i < DIM / 4; ++i) {
            float4 q = q4[i];
            acc = fma((double)q.x, (double)q.x, acc);
            acc = fma((double)q.y, (double)q.y, acc);
            acc = fma((double)q.z, (double)q.z, acc);
            acc = fma((double)q.w, (double)q.w, acc);
        }
        s_p2d[p] = acc;
        s_p2f[p] = (float)acc;
    }
    __syncthreads();

    const int lane = threadIdx.x & 63;
    const long long stride = (long long)gridDim.x * BLOCK;

    for (long long row = (long long)blockIdx.x * BLOCK + threadIdx.x;
         row - lane < (long long)rows_total;   // wave-uniform exit
         row += stride)
    {
        const int valid = row < (long long)rows_total;
        const long long rrow = valid ? row : (long long)(rows_total - 1);
        const float* frow = feats + rrow * DIM;

        // feature row -> 64 VGPRs, pinned (round-3 lesson: block rematerialization)
        float f[DIM];
        {
            const float4* f4 = (const float4*)frow;
            #pragma unroll
            for (int i = 0; i < DIM / 4; ++i) {
                float4 v = f4[i];
                f[4 * i + 0] = v.x; f[4 * i + 1] = v.y;
                f[4 * i + 2] = v.z; f[4 * i + 3] = v.w;
            }
        }
        #pragma unroll
        for (int k = 0; k < DIM; ++k) asm volatile("" : "+v"(f[k]));

        // ||f||^2 fp32, 4 accumulators (thread-local; no butterfly needed)
        float s0 = 0.f, s1 = 0.f, s2 = 0.f, s3 = 0.f;
        #pragma unroll
        for (int k = 0; k < DIM; k += 4) {
            s0 = fmaf(f[k + 0], f[k + 0], s0);
            s1 = fmaf(f[k + 1], f[k + 1], s1);
            s2 = fmaf(f[k + 2], f[k + 2], s2);
            s3 = fmaf(f[k + 3], f[k + 3], s3);
        }
        const float fsf = (s0 + s1) + (s2 + s3);

        float b1 = 3.4e38f, b2 = 3.4e38f;   // best / 2nd-best msed
        int   bi = 0;
        float iv0 = 0.f, iv1 = 0.f;
        float* orow = out_inv + rrow * PROTOS;

        #pragma unroll 1
        for (int p = 0; p < PROTOS; p += 2) {
            const float4* q4 = (const float4*)&s_pr[p][0];
            const float4* r4 = (const float4*)&s_pr[p + 1][0];
            float a0 = 0.f, a1 = 0.f, a2 = 0.f, a3 = 0.f;
            float c0 = 0.f, c1 = 0.f, c2 = 0.f, c3 = 0.f;
            #pragma unroll
            for (int i = 0; i < DIM / 4; ++i) {
                float4 q = q4[i];   // wave-uniform LDS broadcast, conflict-free
                float4 r = r4[i];
                a0 = fmaf(f[4 * i + 0], q.x, a0);
                a1 = fmaf(f[4 * i + 1], q.y, a1);
                a2 = fmaf(f[4 * i + 2], q.z, a2);
                a3 = fmaf(f[4 * i + 3], q.w, a3);
                c0 = fmaf(f[4 * i + 0], r.x, c0);
                c1 = fmaf(f[4 * i + 1], r.y, c1);
                c2 = fmaf(f[4 * i + 2], r.z, c2);
                c3 = fmaf(f[4 * i + 3], r.w, c3);
            }
            float2 pp = *(const float2*)&s_p2f[p];
            float cra = (a0 + a1) + (a2 + a3);
            float crb = (c0 + c1) + (c2 + c3);
            float m0 = fsf - 2.0f * cra + pp.x;
            float m1 = fsf - 2.0f * crb + pp.y;

            // top-2 tracking, sequential p then p+1 (first-min tie policy)
            bi = (m0 < b1) ? p : bi;
            float hi0 = fmaxf(b1, m0);
            b1 = fminf(b1, m0);
            b2 = fminf(b2, hi0);
            bi = (m1 < b1) ? (p + 1) : bi;
            float hi1 = fmaxf(b1, m1);
            b1 = fminf(b1, m1);
            b2 = fminf(b2, hi1);

            // inv_d: fast rcp + 1 NR (~2^-22 rel err; tolerance is absolute ~19.8)
            float d0 = fmaf(m0, 0.015625f, 1e-5f);
            float d1 = fmaf(m1, 0.015625f, 1e-5f);
            float r0 = __builtin_amdgcn_rcpf(d0);
            float r1 = __builtin_amdgcn_rcpf(d1);
            r0 = r0 * (2.0f - d0 * r0);
            r1 = r1 * (2.0f - d1 * r1);

            if ((p & 2) == 0) { iv0 = r0; iv1 = r1; }
            else if (valid) {
                *(float4*)&orow[p - 2] = make_float4(iv0, iv1, r0, r1);
            }
        }

        const int resc = valid && ((b2 - b1) < MARGIN);
        if (valid && !resc) out_lab[row] = (float)plabels[bi];

        // ---- fp64 rescue, wave-cooperative (ballot loop is wave-uniform) ----
        unsigned long long bal = __ballot(resc);
        while (bal) {
            const int l = __builtin_ctzll(bal);
            bal &= bal - 1;
            const long long rw = (row - lane) + l;
            const float* fr = feats + rw * DIM;

            // fsd: lane load + fp64 xor butterfly (exact validated recipe)
            float fl = fr[lane];
            double fsd = (double)fl * (double)fl;
            #pragma unroll
            for (int s = 32; s > 0; s >>= 1) fsd += __shfl_xor(fsd, s, 64);

            // each lane owns protos {lane, lane+64, lane+128, lane+192}
            double bv = 1e300; int bidx = 0;
            #pragma unroll 1
            for (int j = 0; j < 4; ++j) {
                const int p = lane + 64 * j;
                double d0 = 0.0, d1 = 0.0, d2 = 0.0, d3 = 0.0;
                #pragma unroll
                for (int k = 0; k < DIM; k += 4) {
                    d0 = fma((double)fr[k + 0], (double)s_pr[p][k + 0], d0);
                    d1 = fma((double)fr[k + 1], (double)s_pr[p][k + 1], d1);
                    d2 = fma((double)fr[k + 2], (double)s_pr[p][k + 2], d2);
                    d3 = fma((double)fr[k + 3], (double)s_pr[p][k + 3], d3);
                }
                double crossd = (d0 + d1) + (d2 + d3);
                double msedd  = fsd - 2.0 * crossd + s_p2d[p];
                if (msedd < bv) { bv = msedd; bidx = p; }  // strict <, j ascending
            }
            // 64-lane min with smallest-index tie-break
            #pragma unroll
            for (int s = 32; s > 0; s >>= 1) {
                double ov = __shfl_xor(bv, s, 64);
                int    oi = __shfl_xor(bidx, s, 64);
                if (ov < bv || (ov == bv && oi < bidx)) { bv = ov; bidx = oi; }
            }
            if (lane == 0) out_lab[rw] = (float)plabels[bidx];
        }
    }
}

extern "C" void kernel_launch(void* const* d_in, const int* in_sizes, int n_in,
                              void* d_out, int out_size, void* d_ws, size_t ws_size,
                              hipStream_t stream) {
    const float* feats  = (const float*)d_in[0];
    const float* protos = (const float*)d_in[1];
    const int*   plab   = (const int*)d_in[2];
    const int rows = in_sizes[0] / DIM;

    float* out_inv = (float*)d_out;
    float* out_lab = out_inv + (size_t)rows * PROTOS;

    dim3 grid(512), block(BLOCK);
    hipLaunchKernelGGL(protonet_kernel, grid, block, 0, stream,
                       feats, protos, plab, out_inv, out_lab, rows);
}

// Round 3
// 663.989 us; speedup vs baseline: 3.4511x; 3.4511x over previous
//
#include <hip/hip_runtime.h>

// BaseProtonet: inv_d[n,p] = 1/(mse(f_n,proto_p)+1e-5), labels[n] = plabels[argmax_p inv_d]
// msed = ||f||^2 - 2 f.p + ||p||^2  (= 64*mse), argmax inv_d == argmin msed.
//
// Round 5: thread=row structure, spill-proofed.
//  Round-4 failure: VGPR_Count=64 + FETCH 6.5GB + WRITE 695MB = f[64] spilled to
//  scratch and re-read per proto-pair. Cause: __launch_bounds__ empirical VGPR cap
//  is ~256/arg2 on this toolchain ((256,4)->64, (256,3)->84, (512,4)->64), so
//  (512,4) capped at 64 regs vs ~100 needed. Fix:
//   - __launch_bounds__(256,1) -> cap 256. TWO rows per thread (f0,f1 = 128 regs,
//     total demand ~180, margin ~75) so LDS broadcasts amortize over 2 rows.
//   - grid 512 x 256 thr x 2 rows = 262144 rows in ONE pass (stride loop kept for
//     generality). 2 blocks/CU (LDS 71KB), 2 waves/SIMD.
//   - LDS protos padded [256][68] (row stride 272B, float4-aligned): rescue reads
//     8-way instead of 64-way. p2 prologue reads GLOBAL protos (no LDS conflicts),
//     exact serial-k fp64 order of the validated recipe.
//   - validated numerics unchanged: fp32 4-acc dot, top-2 + MARGIN=0.125 rescue
//     trigger, rcp+1NR inv_d (absmax 0.0039 in round 4), fp64 rescue recipe.
//  Floor: 8.6 GFLOP fp32 = 55us VALU + 270MB writes = 43us (overlap) -> ~85-140us.

#define PROTOS 256
#define DIM 64
#define MARGIN 0.125f
#define BLOCK 256
#define PADW (DIM + 4)          // 68 floats = 272 B row stride, 16B-aligned

__global__ __launch_bounds__(BLOCK, 1)
void protonet_kernel(const float* __restrict__ feats,
                     const float* __restrict__ protos,
                     const int* __restrict__ plabels,
                     float* __restrict__ out_inv,
                     float* __restrict__ out_lab,
                     int rows_total)
{
    __shared__ float  s_pr[PROTOS][PADW];  // 69632 B
    __shared__ float  s_p2f[PROTOS];       // 1 KB
    __shared__ double s_p2d[PROTOS];       // 2 KB

    // ---- stage prototypes into padded LDS (coalesced float4 reads) ----
    {
        const float4* src = (const float4*)protos;
        #pragma unroll
        for (int i = 0; i < (PROTOS * DIM / 4) / BLOCK; ++i) {
            int c  = i * BLOCK + threadIdx.x;      // chunk 0..4095
            int pp = c >> 4, cc = c & 15;
            ((float4*)&s_pr[pp][0])[cc] = src[c];
        }
    }

    // ---- ||p||^2 per proto from GLOBAL (exact validated serial-k fp64 order,
    //      avoids the 64-way LDS conflict of row-per-lane reads) ----
    {
        const int p = threadIdx.x;                 // BLOCK == PROTOS
        const float4* g4 = (const float4*)(protos + p * DIM);
        double acc = 0.0;
        #pragma unroll
        for (int i = 0; i < DIM / 4; ++i) {
            float4 q = g4[i];
            acc = fma((double)q.x, (double)q.x, acc);
            acc = fma((double)q.y, (double)q.y, acc);
            acc = fma((double)q.z, (double)q.z, acc);
            acc = fma((double)q.w, (double)q.w, acc);
        }
        s_p2d[p] = acc;
        s_p2f[p] = (float)acc;
    }
    __syncthreads();

    const int lane = threadIdx.x & 63;

    for (long long base = (long long)blockIdx.x * (2 * BLOCK);
         base < (long long)rows_total;
         base += (long long)gridDim.x * (2 * BLOCK))
    {
        const long long row0 = base + threadIdx.x;
        const long long row1 = base + BLOCK + threadIdx.x;
        const int v0 = row0 < (long long)rows_total;
        const int v1 = row1 < (long long)rows_total;
        const long long r0c = v0 ? row0 : (long long)(rows_total - 1);
        const long long r1c = v1 ? row1 : (long long)(rows_total - 1);

        // two feature rows -> 128 pinned VGPRs
        float f0[DIM], f1[DIM];
        {
            const float4* a4 = (const float4*)(feats + r0c * DIM);
            const float4* b4 = (const float4*)(feats + r1c * DIM);
            #pragma unroll
            for (int i = 0; i < DIM / 4; ++i) {
                float4 x = a4[i];
                f0[4 * i + 0] = x.x; f0[4 * i + 1] = x.y;
                f0[4 * i + 2] = x.z; f0[4 * i + 3] = x.w;
                float4 y = b4[i];
                f1[4 * i + 0] = y.x; f1[4 * i + 1] = y.y;
                f1[4 * i + 2] = y.z; f1[4 * i + 3] = y.w;
            }
        }
        #pragma unroll
        for (int k = 0; k < DIM; ++k) asm volatile("" : "+v"(f0[k]));
        #pragma unroll
        for (int k = 0; k < DIM; ++k) asm volatile("" : "+v"(f1[k]));

        // ||f||^2 fp32, 4 accumulators each (validated order)
        float fsf0, fsf1;
        {
            float s0 = 0.f, s1 = 0.f, s2 = 0.f, s3 = 0.f;
            float t0 = 0.f, t1 = 0.f, t2 = 0.f, t3 = 0.f;
            #pragma unroll
            for (int k = 0; k < DIM; k += 4) {
                s0 = fmaf(f0[k + 0], f0[k + 0], s0);
                s1 = fmaf(f0[k + 1], f0[k + 1], s1);
                s2 = fmaf(f0[k + 2], f0[k + 2], s2);
                s3 = fmaf(f0[k + 3], f0[k + 3], s3);
                t0 = fmaf(f1[k + 0], f1[k + 0], t0);
                t1 = fmaf(f1[k + 1], f1[k + 1], t1);
                t2 = fmaf(f1[k + 2], f1[k + 2], t2);
                t3 = fmaf(f1[k + 3], f1[k + 3], t3);
            }
            fsf0 = (s0 + s1) + (s2 + s3);
            fsf1 = (t0 + t1) + (t2 + t3);
        }

        float b1a = 3.4e38f, b2a = 3.4e38f; int bia = 0;   // row0 top-2
        float b1b = 3.4e38f, b2b = 3.4e38f; int bib = 0;   // row1 top-2
        float iva0 = 0.f, iva1 = 0.f, ivb0 = 0.f, ivb1 = 0.f;
        float* orow0 = out_inv + r0c * PROTOS;
        float* orow1 = out_inv + r1c * PROTOS;

        #pragma unroll 1
        for (int p = 0; p < PROTOS; p += 2) {
            const float4* q4 = (const float4*)&s_pr[p][0];
            const float4* r4 = (const float4*)&s_pr[p + 1][0];
            float a0 = 0.f, a1 = 0.f, a2 = 0.f, a3 = 0.f;   // row0 . proto p
            float c0 = 0.f, c1 = 0.f, c2 = 0.f, c3 = 0.f;   // row0 . proto p+1
            float e0 = 0.f, e1 = 0.f, e2 = 0.f, e3 = 0.f;   // row1 . proto p
            float g0 = 0.f, g1 = 0.f, g2 = 0.f, g3 = 0.f;   // row1 . proto p+1
            #pragma unroll
            for (int i = 0; i < DIM / 4; ++i) {
                float4 q = q4[i];   // wave-uniform LDS broadcast
                float4 r = r4[i];
                a0 = fmaf(f0[4 * i + 0], q.x, a0);
                a1 = fmaf(f0[4 * i + 1], q.y, a1);
                a2 = fmaf(f0[4 * i + 2], q.z, a2);
                a3 = fmaf(f0[4 * i + 3], q.w, a3);
                c0 = fmaf(f0[4 * i + 0], r.x, c0);
                c1 = fmaf(f0[4 * i + 1], r.y, c1);
                c2 = fmaf(f0[4 * i + 2], r.z, c2);
                c3 = fmaf(f0[4 * i + 3], r.w, c3);
                e0 = fmaf(f1[4 * i + 0], q.x, e0);
                e1 = fmaf(f1[4 * i + 1], q.y, e1);
                e2 = fmaf(f1[4 * i + 2], q.z, e2);
                e3 = fmaf(f1[4 * i + 3], q.w, e3);
                g0 = fmaf(f1[4 * i + 0], r.x, g0);
                g1 = fmaf(f1[4 * i + 1], r.y, g1);
                g2 = fmaf(f1[4 * i + 2], r.z, g2);
                g3 = fmaf(f1[4 * i + 3], r.w, g3);
            }
            float2 pp = *(const float2*)&s_p2f[p];
            float m0a = fsf0 - 2.0f * ((a0 + a1) + (a2 + a3)) + pp.x;
            float m1a = fsf0 - 2.0f * ((c0 + c1) + (c2 + c3)) + pp.y;
            float m0b = fsf1 - 2.0f * ((e0 + e1) + (e2 + e3)) + pp.x;
            float m1b = fsf1 - 2.0f * ((g0 + g1) + (g2 + g3)) + pp.y;

            // top-2 tracking (sequential p then p+1; ties keep earlier index)
            bia = (m0a < b1a) ? p : bia;
            float h;
            h = fmaxf(b1a, m0a); b1a = fminf(b1a, m0a); b2a = fminf(b2a, h);
            bia = (m1a < b1a) ? (p + 1) : bia;
            h = fmaxf(b1a, m1a); b1a = fminf(b1a, m1a); b2a = fminf(b2a, h);
            bib = (m0b < b1b) ? p : bib;
            h = fmaxf(b1b, m0b); b1b = fminf(b1b, m0b); b2b = fminf(b2b, h);
            bib = (m1b < b1b) ? (p + 1) : bib;
            h = fmaxf(b1b, m1b); b1b = fminf(b1b, m1b); b2b = fminf(b2b, h);

            // inv_d: rcp + 1 Newton (validated round 4, absmax 0.0039)
            float d0a = fmaf(m0a, 0.015625f, 1e-5f);
            float d1a = fmaf(m1a, 0.015625f, 1e-5f);
            float d0b = fmaf(m0b, 0.015625f, 1e-5f);
            float d1b = fmaf(m1b, 0.015625f, 1e-5f);
            float r0a = __builtin_amdgcn_rcpf(d0a); r0a = r0a * (2.0f - d0a * r0a);
            float r1a = __builtin_amdgcn_rcpf(d1a); r1a = r1a * (2.0f - d1a * r1a);
            float r0b = __builtin_amdgcn_rcpf(d0b); r0b = r0b * (2.0f - d0b * r0b);
            float r1b = __builtin_amdgcn_rcpf(d1b); r1b = r1b * (2.0f - d1b * r1b);

            if ((p & 2) == 0) { iva0 = r0a; iva1 = r1a; ivb0 = r0b; ivb1 = r1b; }
            else {
                if (v0) *(float4*)&orow0[p - 2] = make_float4(iva0, iva1, r0a, r1a);
                if (v1) *(float4*)&orow1[p - 2] = make_float4(ivb0, ivb1, r0b, r1b);
            }
        }

        const int resc0 = v0 && ((b2a - b1a) < MARGIN);
        const int resc1 = v1 && ((b2b - b1b) < MARGIN);
        if (v0 && !resc0) out_lab[row0] = (float)plabels[bia];
        if (v1 && !resc1) out_lab[row1] = (float)plabels[bib];

        // ---- fp64 rescue, wave-cooperative (exact validated recipe) ----
        #pragma unroll 1
        for (int half = 0; half < 2; ++half) {
            unsigned long long bal = __ballot(half ? resc1 : resc0);
            const long long wbase = (half ? row1 : row0) - lane;
            while (bal) {
                const int l = __builtin_ctzll(bal);
                bal &= bal - 1;
                const long long rw = wbase + l;
                const float* fr = feats + rw * DIM;

                float fl = fr[lane];
                double fsd = (double)fl * (double)fl;
                #pragma unroll
                for (int s = 32; s > 0; s >>= 1) fsd += __shfl_xor(fsd, s, 64);

                double bv = 1e300; int bidx = 0;
                #pragma unroll 1
                for (int j = 0; j < 4; ++j) {
                    const int p = lane + 64 * j;
                    const float4* pr4 = (const float4*)&s_pr[p][0];
                    double d0 = 0.0, d1 = 0.0, d2 = 0.0, d3 = 0.0;
                    #pragma unroll
                    for (int i = 0; i < DIM / 4; ++i) {
                        float4 q = pr4[i];   // 8-way spread via PADW
                        d0 = fma((double)fr[4 * i + 0], (double)q.x, d0);
                        d1 = fma((double)fr[4 * i + 1], (double)q.y, d1);
                        d2 = fma((double)fr[4 * i + 2], (double)q.z, d2);
                        d3 = fma((double)fr[4 * i + 3], (double)q.w, d3);
                    }
                    double crossd = (d0 + d1) + (d2 + d3);
                    double msedd  = fsd - 2.0 * crossd + s_p2d[p];
                    if (msedd < bv) { bv = msedd; bidx = p; }   // strict <, j asc
                }
                #pragma unroll
                for (int s = 32; s > 0; s >>= 1) {
                    double ov = __shfl_xor(bv, s, 64);
                    int    oi = __shfl_xor(bidx, s, 64);
                    if (ov < bv || (ov == bv && oi < bidx)) { bv = ov; bidx = oi; }
                }
                if (lane == 0) out_lab[rw] = (float)plabels[bidx];
            }
        }
    }
}

extern "C" void kernel_launch(void* const* d_in, const int* in_sizes, int n_in,
                              void* d_out, int out_size, void* d_ws, size_t ws_size,
                              hipStream_t stream) {
    const float* feats  = (const float*)d_in[0];
    const float* protos = (const float*)d_in[1];
    const int*   plab   = (const int*)d_in[2];
    const int rows = in_sizes[0] / DIM;

    float* out_inv = (float*)d_out;
    float* out_lab = out_inv + (size_t)rows * PROTOS;

    int grid = (rows + 2 * BLOCK - 1) / (2 * BLOCK);   // 512 for N=262144
    if (grid > 4096) grid = 4096;
    hipLaunchKernelGGL(protonet_kernel, dim3(grid), dim3(BLOCK), 0, stream,
                       feats, protos, plab, out_inv, out_lab, rows);
}